// Round 13
// baseline (32.443 us; speedup 1.0000x reference)
//
#include <hip/hip_runtime.h>

// Problem constants (fixed by setup_inputs):
//   x: (64,1,8,8) f32 = 16 KB TOTAL; KH=KW=5 -> oh=ow=4
//   rows n = b*16 + s, s = oy*4+ox, N = 1024; feat[n,k] = x[b*64+(oy+i)*8+(ox+j)], k=i*5+j
//   idx0:(128,36,6) in [0,25), lut0:(128,36,64)
//   idx1:(128, 6,6) in [0,36), lut1:(128, 6,64)
//   idx2:(128, 1,6) in [0, 6), lut2:(128, 1,64)
//   out[b,t,oy,ox] = b*2048 + t*16 + s
#define T_TREES 128
#define M0 36
#define M1 6
#define NNODES 43
#define XPAD 68
#define SLUT_ELEMS (T_TREES * NNODES * 64)   // 1.41 MB

__device__ __forceinline__ float sigmoidf(float v) {
    return 1.f / (1.f + __expf(-v));
}

// ---------------- pre-pass: slut[t][node][64] = sigmoid(lut) ----------------
__global__ __launch_bounds__(256) void sig_kernel(
    const float* __restrict__ lut0, const float* __restrict__ lut1,
    const float* __restrict__ lut2, float* __restrict__ slut) {
    int i4 = blockIdx.x * 256 + threadIdx.x;   // 88064 float4s, grid exact
    int j4 = i4 & 15;
    int tn = i4 >> 4;          // t*43 + node
    int t = tn / NNODES;
    int node = tn - t * NNODES;
    const float4* src;
    if (node < M0)            src = (const float4*)lut0 + (t * M0 + node) * 16 + j4;
    else if (node < M0 + M1)  src = (const float4*)lut1 + (t * M1 + (node - M0)) * 16 + j4;
    else                      src = (const float4*)lut2 + t * 16 + j4;
    float4 v = *src;
    float4 r;
    r.x = sigmoidf(v.x); r.y = sigmoidf(v.y);
    r.z = sigmoidf(v.z); r.w = sigmoidf(v.w);
    reinterpret_cast<float4*>(slut)[i4] = r;
}

// Trilinear contraction; sl is a WAVE-UNIFORM pointer into the pre-sigmoided
// global table -> each float4 read compiles to s_load (SGPR-transient, zero
// VGPR footprint). Each FMA reads 1 SGPR + VGPRs (legal operand mix).
__device__ __forceinline__ float lut_node_u(const float* __restrict__ sl,
                                            float a, float b, float c,
                                            float d, float e, float f) {
    float wa[4], wb[4], wc[4];
    { float ab = a * b; wa[3] = ab; wa[2] = a - ab; wa[1] = b - ab; wa[0] = (1.f - a) - wa[1]; }
    { float cd = c * d; wb[3] = cd; wb[2] = c - cd; wb[1] = d - cd; wb[0] = (1.f - c) - wb[1]; }
    { float ef = e * f; wc[3] = ef; wc[2] = e - ef; wc[1] = f - ef; wc[0] = (1.f - e) - wc[1]; }
    float acc = 0.f;
#pragma unroll
    for (int p = 0; p < 4; ++p) {
        float tp = 0.f;
#pragma unroll
        for (int q = 0; q < 4; ++q) {
            float4 P = *reinterpret_cast<const float4*>(sl + p * 16 + q * 4);
            float tq = P.x * wc[0] + P.y * wc[1] + P.z * wc[2] + P.w * wc[3];
            tp += tq * wb[q];
        }
        acc += tp * wa[p];
    }
    return acc;
}

// ===== fused 3-layer kernel: block = (tree t, 64-row chunk) =====
// The occupancy round: LDS only 11.9 KB and P never touches VGPRs, so the
// working set is ~50 VGPRs -> 8 waves/SIMD resident (vs 2-4 in ALL prior
// rounds, which pinned VALUBusy at 26-35%). Grid 2048 = exactly 8 blocks/CU,
// one pass. Wave w owns 9 layer-0 nodes (node id wave-uniform -> idx/P loads
// are scalar); gathers are LDS columns at lane=row -> <=2-way banks (free).
__global__ __launch_bounds__(256) void fused_kernel(
    const float* __restrict__ x, const int* __restrict__ idx0,
    const int* __restrict__ idx1, const int* __restrict__ idx2,
    const float* __restrict__ slut, float* __restrict__ out) {
    __shared__ float xs[4 * XPAD];        // 1088 B: this chunk's 4 images
    __shared__ float h0s[M0 * 64];        // 9216 B
    __shared__ float h1s[M1 * 64];        // 1536 B   => 11840 B total

    const int tid = threadIdx.x;
    const int bx = blockIdx.x;            // bx = chunk*128 + t: tree t's 16
    const int t = bx & 127;               // chunks all land on XCD t%8
    const int chunk = bx >> 7;            // [0,16)

    // stage 4 images (256 floats, 1/thread, coalesced)
    xs[(tid >> 6) * XPAD + (tid & 63)] = x[chunk * 256 + tid];
    __syncthreads();

    const int w = __builtin_amdgcn_readfirstlane(tid >> 6);  // wave id 0..3
    const int r = tid & 63;               // local row = lane
    const int xb = (r >> 4) * XPAD + ((r >> 2) & 3) * 8 + (r & 3);
    const float* __restrict__ slt = slut + t * (NNODES * 64);

    // ---- layer 0: wave w -> nodes 9w .. 9w+8, 64 rows lane-parallel ----
#pragma unroll 1
    for (int k = 0; k < 9; ++k) {
        const int m = w * 9 + k;
        const int* __restrict__ id = idx0 + (t * M0 + m) * 6;  // uniform -> s_load
        float g[6];
#pragma unroll
        for (int j = 0; j < 6; ++j) {
            int kk = id[j];
            int ii = (kk * 13) >> 6;      // kk/5 for kk in [0,25)
            g[j] = xs[xb + kk + 3 * ii];  // window offset i*8+j
        }
        h0s[m * 64 + r] = lut_node_u(slt + m * 64, g[0], g[1], g[2], g[3], g[4], g[5]);
    }
    __syncthreads();

    // ---- layer 1: wave0: nodes 0,4; wave1: 1,5; wave2: 2; wave3: 3 ----
#pragma unroll 1
    for (int m1 = w; m1 < M1; m1 += 4) {
        const int* __restrict__ id = idx1 + (t * M1 + m1) * 6;
        float g[6];
#pragma unroll
        for (int j = 0; j < 6; ++j) g[j] = h0s[id[j] * 64 + r];
        h1s[m1 * 64 + r] = lut_node_u(slt + (M0 + m1) * 64, g[0], g[1], g[2], g[3], g[4], g[5]);
    }
    __syncthreads();

    // ---- layer 2: wave 0 only ----
    if (w == 0) {
        const int* __restrict__ id = idx2 + t * 6;
        float g[6];
#pragma unroll
        for (int j = 0; j < 6; ++j) g[j] = h1s[id[j] * 64 + r];
        float o = lut_node_u(slt + (M0 + M1) * 64, g[0], g[1], g[2], g[3], g[4], g[5]);
        int brow = chunk * 4 + (r >> 4);
        out[brow * (T_TREES * 16) + t * 16 + (r & 15)] = o;
    }
}

// ===== fallback (ws too small): self-contained single kernel =====
__global__ __launch_bounds__(128) void clut_fb_kernel(
    const float* __restrict__ x,
    const int* __restrict__ idx0, const float* __restrict__ lut0,
    const int* __restrict__ idx1, const float* __restrict__ lut1,
    const int* __restrict__ idx2, const float* __restrict__ lut2,
    float* __restrict__ out) {
    __shared__ __align__(16) float slut[NNODES * 64];
    __shared__ float feat[25 * 128];
    __shared__ float h0[M0 * 128];
    __shared__ float h1[M1 * 128];

    const int tid = threadIdx.x;
    const int t = blockIdx.y;
    for (int i = tid; i < NNODES * 64; i += 128) {
        float v;
        if (i < M0 * 64)              v = lut0[t * (M0 * 64) + i];
        else if (i < (M0 + M1) * 64)  v = lut1[t * (M1 * 64) + (i - M0 * 64)];
        else                          v = lut2[t * 64 + (i - (M0 + M1) * 64)];
        slut[i] = sigmoidf(v);
    }
    const int n = blockIdx.x * 128 + tid;
    const int b = n >> 4, s = n & 15;
    const float* xb = x + b * 64 + (s >> 2) * 8 + (s & 3);
#pragma unroll
    for (int i = 0; i < 5; ++i)
#pragma unroll
        for (int j = 0; j < 5; ++j)
            feat[(i * 5 + j) * 128 + tid] = xb[i * 8 + j];
    __syncthreads();
    for (int m = 0; m < M0; ++m) {
        const int* id = idx0 + (t * M0 + m) * 6;
        h0[m * 128 + tid] = lut_node_u(slut + m * 64,
            feat[id[0] * 128 + tid], feat[id[1] * 128 + tid], feat[id[2] * 128 + tid],
            feat[id[3] * 128 + tid], feat[id[4] * 128 + tid], feat[id[5] * 128 + tid]);
    }
    for (int m = 0; m < M1; ++m) {
        const int* id = idx1 + (t * M1 + m) * 6;
        h1[m * 128 + tid] = lut_node_u(slut + (M0 + m) * 64,
            h0[id[0] * 128 + tid], h0[id[1] * 128 + tid], h0[id[2] * 128 + tid],
            h0[id[3] * 128 + tid], h0[id[4] * 128 + tid], h0[id[5] * 128 + tid]);
    }
    {
        const int* id = idx2 + t * 6;
        float o = lut_node_u(slut + (M0 + M1) * 64,
            h1[id[0] * 128 + tid], h1[id[1] * 128 + tid], h1[id[2] * 128 + tid],
            h1[id[3] * 128 + tid], h1[id[4] * 128 + tid], h1[id[5] * 128 + tid]);
        out[b * (T_TREES * 16) + t * 16 + s] = o;
    }
}

extern "C" void kernel_launch(void* const* d_in, const int* in_sizes, int n_in,
                              void* d_out, int out_size, void* d_ws, size_t ws_size,
                              hipStream_t stream) {
    const float* x    = (const float*)d_in[0];
    const int*   idx0 = (const int*)  d_in[1];
    const float* lut0 = (const float*)d_in[2];
    const int*   idx1 = (const int*)  d_in[3];
    const float* lut1 = (const float*)d_in[4];
    const int*   idx2 = (const int*)  d_in[5];
    const float* lut2 = (const float*)d_in[6];
    float* out = (float*)d_out;

    if (ws_size >= (size_t)SLUT_ELEMS * sizeof(float)) {   // 1.41 MB
        float* slut = (float*)d_ws;
        sig_kernel<<<SLUT_ELEMS / 4 / 256, 256, 0, stream>>>(lut0, lut1, lut2, slut); // 344 blocks
        fused_kernel<<<dim3(16 * T_TREES), 256, 0, stream>>>(x, idx0, idx1, idx2, slut, out); // 2048 blocks
    } else {
        clut_fb_kernel<<<dim3(8, T_TREES), 128, 0, stream>>>(x, idx0, lut0, idx1, lut1, idx2, lut2, out);
    }
}

// Round 14
// 24.291 us; speedup vs baseline: 1.3356x; 1.3356x over previous
//
#include <hip/hip_runtime.h>

// Problem constants (fixed by setup_inputs):
//   x: (64,1,8,8) f32 = 16 KB TOTAL; KH=KW=5 -> oh=ow=4
//   rows n = b*16 + s, s = oy*4+ox, N = 1024; feat[n,k] = x[b*64+(oy+i)*8+(ox+j)], k=i*5+j
//   idx0:(128,36,6) in [0,25), lut0:(128,36,64)
//   idx1:(128, 6,6) in [0,36), lut1:(128, 6,64)
//   idx2:(128, 1,6) in [0, 6), lut2:(128, 1,64)
//   out[b,t,oy,ox] = b*2048 + t*16 + s
#define T_TREES 128
#define M0 36
#define M1 6
#define NROWS 1024
#define XPAD 67   // odd LDS image stride -> gather banks sweep residues (~2-way max, free)

typedef float v2f __attribute__((ext_vector_type(2)));

__device__ __forceinline__ float sigmoidf(float v) {
    return 1.f / (1.f + __expf(-v));
}

// Pair-weight, FMA-lean: {(1-a)(1-b),(1-a)b,a(1-b),ab} per 2-row lane.
__device__ __forceinline__ void pair_w(v2f a, v2f b, v2f w[4]) {
    v2f ab = a * b;
    w[3] = ab;
    w[2] = a - ab;
    w[1] = b - ab;
    w[0] = (1.f - a) - w[1];
}

// Trilinear contraction over a row-pair; P in VGPRs (compile-time indexed).
__device__ __forceinline__ v2f lut_node_v2(const float* __restrict__ P,
                                           v2f a, v2f b, v2f c,
                                           v2f d, v2f e, v2f f) {
    v2f wa[4], wb[4], wc[4];
    pair_w(a, b, wa);
    pair_w(c, d, wb);
    pair_w(e, f, wc);
    v2f acc = {0.f, 0.f};
#pragma unroll
    for (int p = 0; p < 4; ++p) {
        v2f tp = {0.f, 0.f};
#pragma unroll
        for (int q = 0; q < 4; ++q) {
            const float* Pq = P + p * 16 + q * 4;
            v2f tq = Pq[0] * wc[0] + Pq[1] * wc[1] + Pq[2] * wc[2] + Pq[3] * wc[3];
            tp += tq * wb[q];
        }
        acc += tp * wa[p];
    }
    return acc;
}

// gather 6 row-pair features for pair id p (helper; adjacent dwords fuse to ds_read2)
__device__ __forceinline__ void gather6(const float* __restrict__ xs,
                                        const int di[6], int p, v2f g[6]) {
    int b = p >> 3;                      // image
    int s = (p & 7) * 2;                 // even position
    int xb = b * XPAD + (s >> 2) * 8 + (s & 3);
#pragma unroll
    for (int j = 0; j < 6; ++j) {
        int a0 = xb + di[j];
        g[j].x = xs[a0];
        g[j].y = xs[a0 + 1];
    }
}

// ===== layer 0: wave-stationary node, row-pair lanes, SW-pipelined gathers =====
// Wave w owns node (t, mg*4+w) for all 1024 rows (8 pair-iters). P batch-loaded
// to 64 VGPRs once per node (the R4 mechanism that took 52->25 us); the only
// per-iter memory is 6 ds_read2 gathers -- now issued ONE ITERATION AHEAD
// (gA/gB double buffer, static indexing) so their ~120cy latency hides under
// the previous iteration's ~90 packed-FMA ops instead of stalling the wave.
__global__ __launch_bounds__(256, 2) void l0_kernel(
    const float* __restrict__ x, const int* __restrict__ idx0,
    const float* __restrict__ lut0, float* __restrict__ h0) {
    __shared__ float xs[64 * XPAD];          // 17152 B
    __shared__ __align__(16) float Ps[4 * 64];

    const int tid = threadIdx.x;
    const int bx = blockIdx.x;               // bx = mg*128 + t (t fast -> XCD locality)
    const int t = bx & 127;
    const int mg = bx >> 7;                  // node group [0,9)

    // stage x (coalesced float4 reads; scalar LDS writes, odd stride)
#pragma unroll
    for (int k = 0; k < 4; ++k) {
        int i4 = tid + k * 256;              // float4 index (16 per image)
        float4 v = reinterpret_cast<const float4*>(x)[i4];
        float* dst = xs + (i4 >> 4) * XPAD + (i4 & 15) * 4;
        dst[0] = v.x; dst[1] = v.y; dst[2] = v.z; dst[3] = v.w;
    }
    Ps[tid] = sigmoidf(lut0[(t * M0 + mg * 4) * 64 + tid]);  // 4 nodes x 64
    __syncthreads();

    const int w = tid >> 6, ln = tid & 63;
    const int m = mg * 4 + w;

    // hoist this wave's P into 64 registers (broadcast ds_read_b128, row-inv)
    float P[64];
#pragma unroll
    for (int i = 0; i < 16; ++i) {
        float4 v = reinterpret_cast<const float4*>(Ps + w * 64)[i];
        P[4 * i] = v.x; P[4 * i + 1] = v.y; P[4 * i + 2] = v.z; P[4 * i + 3] = v.w;
    }

    // wave-uniform idx -> window offsets
    const int* id = idx0 + (t * M0 + m) * 6;
    int di[6];
#pragma unroll
    for (int j = 0; j < 6; ++j) {
        int k = id[j];
        int ii = (k * 13) >> 6;              // k/5 for k in [0,25)
        di[j] = k - 5 * ii + ii * 8;         // i*8 + j window offset
    }

    float* __restrict__ hout = h0 + (t * M0 + m) * NROWS;

    // ---- 2-stage software pipeline over 8 pair-iters (4 x 2-step body) ----
    v2f gA[6], gB[6];
    gather6(xs, di, ln, gA);                 // prologue: iter 0 loads
#pragma unroll
    for (int uu = 0; uu < 4; ++uu) {
        int u0 = 2 * uu, u1 = 2 * uu + 1;
        // step A: issue iter u1 loads, then compute iter u0 from gA
        gather6(xs, di, u1 * 64 + ln, gB);
        {
            v2f r = lut_node_v2(P, gA[0], gA[1], gA[2], gA[3], gA[4], gA[5]);
            *reinterpret_cast<v2f*>(hout + 2 * (u0 * 64 + ln)) = r;
        }
        // step B: issue iter u0+2 loads (unless done), compute iter u1 from gB
        if (uu < 3) gather6(xs, di, (u1 + 1) * 64 + ln, gA);
        {
            v2f r = lut_node_v2(P, gB[0], gB[1], gB[2], gB[3], gB[4], gB[5]);
            *reinterpret_cast<v2f*>(hout + 2 * (u1 * 64 + ln)) = r;
        }
    }
}

// ===== layers 1+2 fused: block = (t, quarter of rows), 512 blocks x 384 thr.
// Both pair-iters' 12 global h0 loads issued BEFORE either compute (vmcnt
// batching); h0 reads XCD-local (writer mg*128+t, reader q*128+t agree mod 8).
__global__ __launch_bounds__(384, 2) void l12_kernel(
    const float* __restrict__ h0, const int* __restrict__ idx1,
    const float* __restrict__ lut1, const int* __restrict__ idx2,
    const float* __restrict__ lut2, float* __restrict__ out) {
    __shared__ __align__(16) float Ps[(M1 + 1) * 64];   // 448 floats
    __shared__ __align__(8) float h1s[M1 * 256];        // 6 KB

    const int tid = threadIdx.x;
    const int bx = blockIdx.x;               // bx = q*128 + t
    const int t = bx & 127;
    const int q = bx >> 7;                   // row quarter [0,4)

    for (int i = tid; i < (M1 + 1) * 64; i += 384) {
        float v = (i < M1 * 64) ? lut1[t * (M1 * 64) + i] : lut2[t * 64 + (i - M1 * 64)];
        Ps[i] = sigmoidf(v);
    }
    __syncthreads();

    const int w = tid >> 6, ln = tid & 63;

    // layer 1: wave w = node w of tree t over 256 rows (2 pairs/lane)
    {
        float P[64];
#pragma unroll
        for (int i = 0; i < 16; ++i) {
            float4 v = reinterpret_cast<const float4*>(Ps + w * 64)[i];
            P[4 * i] = v.x; P[4 * i + 1] = v.y; P[4 * i + 2] = v.z; P[4 * i + 3] = v.w;
        }
        const int* id = idx1 + (t * M1 + w) * 6;
        const float* c[6];
#pragma unroll
        for (int j = 0; j < 6; ++j) c[j] = h0 + (t * M0 + id[j]) * NROWS;

        int r0 = q * 256 + 2 * ln;           // pair-iter 0 row
        int r1 = r0 + 128;                   // pair-iter 1 row
        v2f gA[6], gB[6];
#pragma unroll
        for (int j = 0; j < 6; ++j) gA[j] = *reinterpret_cast<const v2f*>(c[j] + r0);
#pragma unroll
        for (int j = 0; j < 6; ++j) gB[j] = *reinterpret_cast<const v2f*>(c[j] + r1);
        v2f ra = lut_node_v2(P, gA[0], gA[1], gA[2], gA[3], gA[4], gA[5]);
        *reinterpret_cast<v2f*>(h1s + w * 256 + 2 * ln) = ra;
        v2f rb = lut_node_v2(P, gB[0], gB[1], gB[2], gB[3], gB[4], gB[5]);
        *reinterpret_cast<v2f*>(h1s + w * 256 + 2 * ln + 128) = rb;
    }
    __syncthreads();

    // layer 2: 128 threads, one pair each
    if (tid < 128) {
        float P[64];
#pragma unroll
        for (int i = 0; i < 16; ++i) {
            float4 v = reinterpret_cast<const float4*>(Ps + M1 * 64)[i];
            P[4 * i] = v.x; P[4 * i + 1] = v.y; P[4 * i + 2] = v.z; P[4 * i + 3] = v.w;
        }
        const int* id = idx2 + t * 6;
        int rl = 2 * tid;                    // even row within quarter
        v2f g[6];
#pragma unroll
        for (int j = 0; j < 6; ++j)
            g[j] = *reinterpret_cast<const v2f*>(h1s + id[j] * 256 + rl);
        v2f r = lut_node_v2(P, g[0], g[1], g[2], g[3], g[4], g[5]);
        int row = q * 256 + rl;
        int b = row >> 4, s = row & 15;
        *reinterpret_cast<v2f*>(out + b * (T_TREES * 16) + t * 16 + s) = r;
    }
}

// ===== fallback (ws too small): self-contained single kernel =====
__global__ __launch_bounds__(128) void clut_fb_kernel(
    const float* __restrict__ x,
    const int* __restrict__ idx0, const float* __restrict__ lut0,
    const int* __restrict__ idx1, const float* __restrict__ lut1,
    const int* __restrict__ idx2, const float* __restrict__ lut2,
    float* __restrict__ out) {
    __shared__ __align__(16) float slut[43 * 64];
    __shared__ float feat[25 * 128];
    __shared__ float h0[M0 * 128];
    __shared__ float h1[M1 * 128];

    const int tid = threadIdx.x;
    const int t = blockIdx.y;
    for (int i = tid; i < 43 * 64; i += 128) {
        float v;
        if (i < M0 * 64)              v = lut0[t * (M0 * 64) + i];
        else if (i < (M0 + M1) * 64)  v = lut1[t * (M1 * 64) + (i - M0 * 64)];
        else                          v = lut2[t * 64 + (i - (M0 + M1) * 64)];
        slut[i] = sigmoidf(v);
    }
    const int n = blockIdx.x * 128 + tid;
    const int b = n >> 4, s = n & 15;
    const float* xb = x + b * 64 + (s >> 2) * 8 + (s & 3);
#pragma unroll
    for (int i = 0; i < 5; ++i)
#pragma unroll
        for (int j = 0; j < 5; ++j)
            feat[(i * 5 + j) * 128 + tid] = xb[i * 8 + j];
    __syncthreads();
    for (int m = 0; m < M0; ++m) {
        const int* id = idx0 + (t * M0 + m) * 6;
        v2f g[6];
#pragma unroll
        for (int j = 0; j < 6; ++j) { g[j].x = feat[id[j] * 128 + tid]; g[j].y = 0.f; }
        v2f r = lut_node_v2(slut + m * 64, g[0], g[1], g[2], g[3], g[4], g[5]);
        h0[m * 128 + tid] = r.x;
    }
    for (int m = 0; m < M1; ++m) {
        const int* id = idx1 + (t * M1 + m) * 6;
        v2f g[6];
#pragma unroll
        for (int j = 0; j < 6; ++j) { g[j].x = h0[id[j] * 128 + tid]; g[j].y = 0.f; }
        v2f r = lut_node_v2(slut + (M0 + m) * 64, g[0], g[1], g[2], g[3], g[4], g[5]);
        h1[m * 128 + tid] = r.x;
    }
    {
        const int* id = idx2 + t * 6;
        v2f g[6];
#pragma unroll
        for (int j = 0; j < 6; ++j) { g[j].x = h1[id[j] * 128 + tid]; g[j].y = 0.f; }
        v2f r = lut_node_v2(slut + (M0 + M1) * 64, g[0], g[1], g[2], g[3], g[4], g[5]);
        out[b * (T_TREES * 16) + t * 16 + s] = r.x;
    }
}

extern "C" void kernel_launch(void* const* d_in, const int* in_sizes, int n_in,
                              void* d_out, int out_size, void* d_ws, size_t ws_size,
                              hipStream_t stream) {
    const float* x    = (const float*)d_in[0];
    const int*   idx0 = (const int*)  d_in[1];
    const float* lut0 = (const float*)d_in[2];
    const int*   idx1 = (const int*)  d_in[3];
    const float* lut1 = (const float*)d_in[4];
    const int*   idx2 = (const int*)  d_in[5];
    const float* lut2 = (const float*)d_in[6];
    float* out = (float*)d_out;

    const size_t h0_bytes = (size_t)T_TREES * M0 * NROWS * sizeof(float);  // 18.9 MB
    if (ws_size >= h0_bytes) {
        float* h0 = (float*)d_ws;
        l0_kernel<<<dim3((M0 / 4) * T_TREES), 256, 0, stream>>>(x, idx0, lut0, h0);         // 1152 blocks
        l12_kernel<<<dim3(4 * T_TREES), 384, 0, stream>>>(h0, idx1, lut1, idx2, lut2, out); // 512 blocks
    } else {
        clut_fb_kernel<<<dim3(8, T_TREES), 128, 0, stream>>>(x, idx0, lut0, idx1, lut1, idx2, lut2, out);
    }
}

// Round 15
// 22.559 us; speedup vs baseline: 1.4382x; 1.0768x over previous
//
#include <hip/hip_runtime.h>
#include <hip/hip_fp16.h>

// Problem constants (fixed by setup_inputs):
//   x: (64,1,8,8) f32; KH=KW=5 -> oh=ow=4; rows n = b*16 + s, N = 1024
//   feat[n, i*5+j] = x[b*64 + (oy+i)*8 + (ox+j)], s = oy*4+ox
//   idx0:(128,36,6) in [0,25), lut0:(128,36,64)
//   idx1:(128, 6,6) in [0,36), lut1:(128, 6,64)
//   idx2:(128, 1,6) in [0, 6), lut2:(128, 1,64)
//   out[b,t,oy,ox] = b*2048 + t*16 + s
#define T_TREES 128
#define M0 36
#define M1 6
#define NNODES 43
#define XPAD 67   // odd LDS image stride -> gather banks sweep residues (~2-way, free)

typedef float v2f __attribute__((ext_vector_type(2)));

__device__ __forceinline__ float sigmoidf(float v) {
    return 1.f / (1.f + __expf(-v));
}

// Pair-weight, FMA-lean: {(1-a)(1-b),(1-a)b,a(1-b),ab} per 2-row lane.
__device__ __forceinline__ void pair_w(v2f a, v2f b, v2f w[4]) {
    v2f ab = a * b;
    w[3] = ab;
    w[2] = a - ab;
    w[1] = b - ab;
    w[0] = (1.f - a) - w[1];
}

// Trilinear contraction over a row-pair; P in VGPRs (compile-time indexed).
__device__ __forceinline__ v2f lut_node_v2(const float* __restrict__ P,
                                           v2f a, v2f b, v2f c,
                                           v2f d, v2f e, v2f f) {
    v2f wa[4], wb[4], wc[4];
    pair_w(a, b, wa);
    pair_w(c, d, wb);
    pair_w(e, f, wc);
    v2f acc = {0.f, 0.f};
#pragma unroll
    for (int p = 0; p < 4; ++p) {
        v2f tp = {0.f, 0.f};
#pragma unroll
        for (int q = 0; q < 4; ++q) {
            const float* Pq = P + p * 16 + q * 4;
            v2f tq = Pq[0] * wc[0] + Pq[1] * wc[1] + Pq[2] * wc[2] + Pq[3] * wc[3];
            tp += tq * wb[q];
        }
        acc += tp * wa[p];
    }
    return acc;
}

// ===== Single fused kernel: block = (tree t, 256-row quarter), 256 thr =====
// R9's fusion (no 2nd launch, no 19MB h0 HBM round-trip) with the LDS budget
// fixed: quarter-only x staging (4.3 KB, not 17) and h0 stored as f16 pairs
// (18.4 KB, not 36.9; one rounding of [0,1] values ~5e-4 << 1.19e-2 thresh).
// Total 39.9 KB -> 4 blocks/CU x 4 waves = 16 waves/CU, same residency as the
// best split kernel (R14) but with its structural overheads removed. All
// proven mechanisms kept: P batch-hoisted to 64 VGPRs once per node (the
// R4 mechanism), v2f pair math, odd XPAD, t-fast grid for XCD locality.
// (256,2): VGPR cap 256, safely above the ~130-reg body (R5 spill lesson).
__global__ __launch_bounds__(256, 2) void fused_kernel(
    const float* __restrict__ x,
    const int* __restrict__ idx0, const float* __restrict__ lut0,
    const int* __restrict__ idx1, const float* __restrict__ lut1,
    const int* __restrict__ idx2, const float* __restrict__ lut2,
    float* __restrict__ out) {
    __shared__ float xs[16 * XPAD];                  //  4288 B: quarter's 16 images
    __shared__ __align__(16) float Ps[NNODES * 64];  // 11008 B sigmoided LUTs
    __shared__ __half2 h0s[M0 * 128];                // 18432 B (pair-packed f16)
    __shared__ __align__(8) float h1s[M1 * 256];     //  6144 B   => 39872 B total

    const int tid = threadIdx.x;
    const int bx = blockIdx.x;            // bx = q*128 + t (t fast -> XCD locality)
    const int t = bx & 127;
    const int q = bx >> 7;                // row quarter [0,4)

    // ---- prologue: stage 16 images (padded) + sigmoid all 43 node LUTs ----
    const float* __restrict__ xq = x + q * 1024;
    for (int i = tid; i < 1024; i += 256)
        xs[(i >> 6) * XPAD + (i & 63)] = xq[i];
    for (int i = tid; i < NNODES * 64; i += 256) {
        float v;
        if (i < M0 * 64)              v = lut0[t * (M0 * 64) + i];
        else if (i < (M0 + M1) * 64)  v = lut1[t * (M1 * 64) + (i - M0 * 64)];
        else                          v = lut2[t * 64 + (i - (M0 + M1) * 64)];
        Ps[i] = sigmoidf(v);
    }
    __syncthreads();

    const int w = tid >> 6, ln = tid & 63;

    // ---- layer 0: wave w -> nodes 9w..9w+8; 128 pairs (2 iters) each ----
#pragma unroll 1
    for (int k = 0; k < 9; ++k) {
        const int m = w * 9 + k;
        // P batch-hoist: 16 broadcast ds_read_b128, amortized over 2 pair-iters
        float P[64];
#pragma unroll
        for (int i = 0; i < 16; ++i) {
            float4 v = reinterpret_cast<const float4*>(Ps + m * 64)[i];
            P[4 * i] = v.x; P[4 * i + 1] = v.y; P[4 * i + 2] = v.z; P[4 * i + 3] = v.w;
        }
        const int* id = idx0 + (t * M0 + m) * 6;   // wave-uniform -> scalar
        int di[6];
#pragma unroll
        for (int j = 0; j < 6; ++j) {
            int kk = id[j];
            int ii = (kk * 13) >> 6;      // kk/5 for kk in [0,25)
            di[j] = kk - 5 * ii + ii * 8; // i*8 + j window offset
        }
#pragma unroll
        for (int u = 0; u < 2; ++u) {
            int p = u * 64 + ln;          // local pair: rows 2p,2p+1
            int b = p >> 3;               // local image [0,16)
            int s = (p & 7) * 2;          // even position
            int xb = b * XPAD + (s >> 2) * 8 + (s & 3);
            v2f g[6];
#pragma unroll
            for (int j = 0; j < 6; ++j) {
                int a0 = xb + di[j];
                g[j].x = xs[a0];          // fuses -> ds_read2_b32
                g[j].y = xs[a0 + 1];
            }
            v2f r = lut_node_v2(P, g[0], g[1], g[2], g[3], g[4], g[5]);
            h0s[m * 128 + p] = __floats2half2_rn(r.x, r.y);
        }
    }
    __syncthreads();

    // ---- layer 1: wave0: nodes 0,4; wave1: 1,5; wave2: 2; wave3: 3 ----
#pragma unroll 1
    for (int m1 = w; m1 < M1; m1 += 4) {
        float P[64];
#pragma unroll
        for (int i = 0; i < 16; ++i) {
            float4 v = reinterpret_cast<const float4*>(Ps + (M0 + m1) * 64)[i];
            P[4 * i] = v.x; P[4 * i + 1] = v.y; P[4 * i + 2] = v.z; P[4 * i + 3] = v.w;
        }
        const int* id = idx1 + (t * M1 + m1) * 6;
#pragma unroll
        for (int u = 0; u < 2; ++u) {
            int p = u * 64 + ln;
            v2f g[6];
#pragma unroll
            for (int j = 0; j < 6; ++j) {
                float2 f = __half22float2(h0s[id[j] * 128 + p]);
                g[j].x = f.x; g[j].y = f.y;
            }
            v2f r = lut_node_v2(P, g[0], g[1], g[2], g[3], g[4], g[5]);
            *reinterpret_cast<v2f*>(h1s + m1 * 256 + 2 * p) = r;
        }
    }
    __syncthreads();

    // ---- layer 2: first 2 waves, one pair per thread ----
    if (tid < 128) {
        float P[64];
#pragma unroll
        for (int i = 0; i < 16; ++i) {
            float4 v = reinterpret_cast<const float4*>(Ps + (M0 + M1) * 64)[i];
            P[4 * i] = v.x; P[4 * i + 1] = v.y; P[4 * i + 2] = v.z; P[4 * i + 3] = v.w;
        }
        const int* id = idx2 + t * 6;
        int rl = 2 * tid;                 // local even row
        v2f g[6];
#pragma unroll
        for (int j = 0; j < 6; ++j)
            g[j] = *reinterpret_cast<const v2f*>(h1s + id[j] * 256 + rl);
        v2f o = lut_node_v2(P, g[0], g[1], g[2], g[3], g[4], g[5]);
        int row = q * 256 + rl;
        int b = row >> 4, s = row & 15;
        *reinterpret_cast<v2f*>(out + b * (T_TREES * 16) + t * 16 + s) = o;
    }
}

extern "C" void kernel_launch(void* const* d_in, const int* in_sizes, int n_in,
                              void* d_out, int out_size, void* d_ws, size_t ws_size,
                              hipStream_t stream) {
    const float* x    = (const float*)d_in[0];
    const int*   idx0 = (const int*)  d_in[1];
    const float* lut0 = (const float*)d_in[2];
    const int*   idx1 = (const int*)  d_in[3];
    const float* lut1 = (const float*)d_in[4];
    const int*   idx2 = (const int*)  d_in[5];
    const float* lut2 = (const float*)d_in[6];
    float* out = (float*)d_out;

    fused_kernel<<<dim3(4 * T_TREES), 256, 0, stream>>>(
        x, idx0, lut0, idx1, lut1, idx2, lut2, out);   // 512 blocks = 4/CU, one pass
}